// Round 6
// baseline (439.730 us; speedup 1.0000x reference)
//
#include <hip/hip_runtime.h>
#include <math.h>

#define BATCH 4096
#define DIN   2048
#define DOUT  2048
#define DEPTH 16

typedef unsigned short u16;
typedef __attribute__((ext_vector_type(8))) short short8;  // 8 bf16 = 4 VGPRs (guide §3)
typedef __attribute__((ext_vector_type(4))) float f32x4;

// ---------- helpers ----------

__device__ static inline unsigned bf16_rn(float x) {
    unsigned u = __float_as_uint(x);
    return (u + 0x7FFFu + ((u >> 16) & 1u)) >> 16;  // RN-even to bf16 bits
}

__device__ static inline float tanh_fast(float z) {
    float zc = fminf(fmaxf(z, -15.0f), 15.0f);
    float e = __builtin_amdgcn_exp2f(zc * 2.8853900817779268f);  // exp(2z)
    return (e - 1.0f) * __builtin_amdgcn_rcpf(e + 1.0f);
}

__device__ static inline void async16(u16* lds, const u16* g) {
    __builtin_amdgcn_global_load_lds(
        (const __attribute__((address_space(1))) void*)g,
        (__attribute__((address_space(3))) void*)lds, 16, 0, 0);
}

// ---------- probs: probs[j] = (prod cos(W[d,j,g]))^2 / DIN ----------
__global__ __launch_bounds__(256) void probs_kernel(const float* __restrict__ W,
                                                    float* __restrict__ probs) {
    int tid = threadIdx.x;
    int jl = tid >> 4, d = tid & 15;
    int j = blockIdx.x * 16 + jl;
    const float* p = W + (size_t)d * DIN * DOUT + (size_t)j * DOUT;
    float pr = cosf(p[0]) * cosf(p[1]) * cosf(p[2]);
#pragma unroll
    for (int off = 1; off < 16; off <<= 1) pr *= __shfl_xor(pr, off, 16);
    if (d == 0) probs[j] = pr * pr * (1.0f / (float)DIN);
}

// ---------- x -> hi/lo bf16 (RN split) ----------
__global__ __launch_bounds__(256) void convert_x_kernel(const float* __restrict__ x,
                                                        u16* __restrict__ xh,
                                                        u16* __restrict__ xl) {
    int i = (blockIdx.x * 256 + threadIdx.x) * 4;
    float4 v = *(const float4*)(x + i);
    ushort4 h, l;
    float vv[4] = {v.x, v.y, v.z, v.w};
    u16 hh[4], ll[4];
#pragma unroll
    for (int c = 0; c < 4; ++c) {
        unsigned hb = bf16_rn(vv[c]);
        hh[c] = (u16)hb;
        float r = vv[c] - __uint_as_float(hb << 16);
        ll[c] = (u16)bf16_rn(r);
    }
    h.x = hh[0]; h.y = hh[1]; h.z = hh[2]; h.w = hh[3];
    l.x = ll[0]; l.y = ll[1]; l.z = ll[2]; l.w = ll[3];
    *(ushort4*)(xh + i) = h;
    *(ushort4*)(xl + i) = l;
}

// ---------- W[k][n] -> Wt_hi/Wt_lo[n][k] (transpose + RN split) ----------
__global__ __launch_bounds__(256) void transpose_w_kernel(const float* __restrict__ W,
                                                          u16* __restrict__ wh,
                                                          u16* __restrict__ wl) {
    __shared__ float t[32][33];
    int n0 = blockIdx.x * 32, k0 = blockIdx.y * 32;
    int tx = threadIdx.x & 31, ty = threadIdx.x >> 5;  // ty 0..7
#pragma unroll
    for (int i = 0; i < 4; ++i)
        t[ty + i * 8][tx] = W[(size_t)(k0 + ty + i * 8) * DOUT + n0 + tx];
    __syncthreads();
#pragma unroll
    for (int i = 0; i < 4; ++i) {
        float v = t[tx][ty + i * 8];
        size_t o = (size_t)(n0 + ty + i * 8) * DIN + k0 + tx;
        unsigned hb = bf16_rn(v);
        wh[o] = (u16)hb;
        float r = v - __uint_as_float(hb << 16);
        wl[o] = (u16)bf16_rn(r);
    }
}

// ---------- MFMA GEMM: C = tanh(x@W + bias + probs), bf16x3 ----------
// v3: 128x128 tile, 8 waves (2M x 4N, per-wave 64x32), BK=32, THREE LDS
// buffers (96KB, 1 block/CU, 8 waves/CU) + depth-2 prefetch with COUNTED
// vmcnt (T4, m218) and raw s_barrier — loads never drain to 0 in the loop.
// Per K-step:  s_waitcnt vmcnt(4)   (tile t landed; tile t+1 in flight)
//              s_barrier            (all waves' tile-t chunks visible)
//              issue tile t+2 DMA   (into buf[(t+2)%3] = buf[(t-1)%3]; safe:
//                                    all waves past barrier t => iter t-1
//                                    reads consumed before their barrier)
//              ds_read frags, 24 MFMA (setprio 1)
// Buffer layout (u16 offs): Ah[0,4k) Al[4k,8k) Bh[8k,12k) Bl[12k,16k).
// Rows of 32 bf16 (64B), XOR swizzle phys_quad = quad ^ ((row>>1)&3),
// pre-swizzled global source (rule #21). Same frag math as verified v2.
__global__ __launch_bounds__(512, 2) void gemm_mfma_kernel(
    const u16* __restrict__ xh, const u16* __restrict__ xl,
    const u16* __restrict__ wh, const u16* __restrict__ wl,
    const float* __restrict__ bias, const float* __restrict__ probs,
    float* __restrict__ C)
{
    __shared__ __align__(16) u16 lds[3][16384];  // 96KB -> 1 block/CU

    const int tid = threadIdx.x;
    const int lane = tid & 63;
    const int wave = tid >> 6;  // 0..7

    // T1: bijective XCD swizzle (512 blocks, 512 % 8 == 0).
    const int bid = blockIdx.x;
    const int swz = (bid & 7) * 64 + (bid >> 3);
    const int bR = (swz & 31) * 128;
    const int bC = (swz >> 5) * 128;

    // Staging: arr = wave>>1 (0 Ah, 1 Al, 2 Bh, 3 Bl), half = wave&1.
    // Each wave stages 4 chunks of 1KB per K-tile (rows half*64 .. +63).
    const int arr = wave >> 1, half = wave & 1;
    const u16* gsrc = (arr == 0) ? xh + (size_t)bR * DIN
                    : (arr == 1) ? xl + (size_t)bR * DIN
                    : (arr == 2) ? wh + (size_t)bC * DIN
                                 : wl + (size_t)bC * DIN;
    gsrc += (size_t)(half * 64) * DIN;

    int goff[4];
#pragma unroll
    for (int i = 0; i < 4; ++i) {
        int row = i * 16 + (lane >> 2);       // local row within this wave's 64
        int fullrow = half * 64 + row;
        int lq = (lane & 3) ^ ((fullrow >> 1) & 3);  // pre-swizzled source
        goff[i] = row * DIN + lq * 8;
    }
    const int stoff = arr * 4096 + half * 2048;  // u16 offset within a buffer

    // Per-wave output: rows wm*64 (4 m-tiles), cols wn*32 (2 n-tiles).
    const int wm = wave >> 2, wn = wave & 3;
    const int colL = lane & 15, quad = lane >> 4;

    int aoff[4], boff[2];
#pragma unroll
    for (int mt = 0; mt < 4; ++mt) {
        int r = wm * 64 + mt * 16 + colL;
        aoff[mt] = r * 32 + (quad ^ ((r >> 1) & 3)) * 8;
    }
#pragma unroll
    for (int nt = 0; nt < 2; ++nt) {
        int r = wn * 32 + nt * 16 + colL;
        boff[nt] = 8192 + r * 32 + (quad ^ ((r >> 1) & 3)) * 8;
    }

    f32x4 acc[4][2];
#pragma unroll
    for (int mt = 0; mt < 4; ++mt)
#pragma unroll
        for (int nt = 0; nt < 2; ++nt) acc[mt][nt] = (f32x4){0.f, 0.f, 0.f, 0.f};

    // prologue: issue tiles 0 -> buf0, 1 -> buf1 (8 loads in flight)
#pragma unroll
    for (int i = 0; i < 4; ++i) async16(&lds[0][0] + stoff + i * 512, gsrc + goff[i]);
#pragma unroll
    for (int i = 0; i < 4; ++i) async16(&lds[1][0] + stoff + i * 512, gsrc + goff[i] + 32);

#pragma unroll 1
    for (int t = 0; t < 63; ++t) {
        const int cur = t % 3;

        asm volatile("s_waitcnt vmcnt(4)" ::: "memory");  // tile t done, t+1 flying
        __builtin_amdgcn_s_barrier();
        asm volatile("" ::: "memory");
        __builtin_amdgcn_sched_barrier(0);

        // issue tile t+2 into buf[(t+2)%3] (overlaps reads + MFMA + next step)
        if (t < 62) {
            u16* st = &lds[(t + 2) % 3][0] + stoff;
            const int kk = (t + 2) * 32;
#pragma unroll
            for (int i = 0; i < 4; ++i) async16(st + i * 512, gsrc + goff[i] + kk);
        }

        const u16* Lb = &lds[cur][0];
        short8 ah[4], al[4], bh[2], bl[2];
#pragma unroll
        for (int mt = 0; mt < 4; ++mt) {
            ah[mt] = *(const short8*)(Lb + aoff[mt]);
            al[mt] = *(const short8*)(Lb + 4096 + aoff[mt]);
        }
#pragma unroll
        for (int nt = 0; nt < 2; ++nt) {
            bh[nt] = *(const short8*)(Lb + boff[nt]);
            bl[nt] = *(const short8*)(Lb + 4096 + boff[nt]);
        }

        __builtin_amdgcn_s_setprio(1);
#pragma unroll
        for (int mt = 0; mt < 4; ++mt)
#pragma unroll
            for (int nt = 0; nt < 2; ++nt) {
                acc[mt][nt] = __builtin_amdgcn_mfma_f32_16x16x32_bf16(
                    ah[mt], bh[nt], acc[mt][nt], 0, 0, 0);
                acc[mt][nt] = __builtin_amdgcn_mfma_f32_16x16x32_bf16(
                    ah[mt], bl[nt], acc[mt][nt], 0, 0, 0);
                acc[mt][nt] = __builtin_amdgcn_mfma_f32_16x16x32_bf16(
                    al[mt], bh[nt], acc[mt][nt], 0, 0, 0);
            }
        __builtin_amdgcn_s_setprio(0);
    }

    // peeled final K-step (t = 63, buf 0): full drain, no prefetch
    {
        asm volatile("s_waitcnt vmcnt(0)" ::: "memory");
        __builtin_amdgcn_s_barrier();
        asm volatile("" ::: "memory");
        __builtin_amdgcn_sched_barrier(0);

        const u16* Lb = &lds[0][0];
        short8 ah[4], al[4], bh[2], bl[2];
#pragma unroll
        for (int mt = 0; mt < 4; ++mt) {
            ah[mt] = *(const short8*)(Lb + aoff[mt]);
            al[mt] = *(const short8*)(Lb + 4096 + aoff[mt]);
        }
#pragma unroll
        for (int nt = 0; nt < 2; ++nt) {
            bh[nt] = *(const short8*)(Lb + boff[nt]);
            bl[nt] = *(const short8*)(Lb + 4096 + boff[nt]);
        }
#pragma unroll
        for (int mt = 0; mt < 4; ++mt)
#pragma unroll
            for (int nt = 0; nt < 2; ++nt) {
                acc[mt][nt] = __builtin_amdgcn_mfma_f32_16x16x32_bf16(
                    ah[mt], bh[nt], acc[mt][nt], 0, 0, 0);
                acc[mt][nt] = __builtin_amdgcn_mfma_f32_16x16x32_bf16(
                    ah[mt], bl[nt], acc[mt][nt], 0, 0, 0);
                acc[mt][nt] = __builtin_amdgcn_mfma_f32_16x16x32_bf16(
                    al[mt], bh[nt], acc[mt][nt], 0, 0, 0);
            }
    }

    // epilogue: C/D map col=lane&15, row=quad*4+reg (verified m89/m91)
    float bp[2];
#pragma unroll
    for (int nt = 0; nt < 2; ++nt) {
        int c = bC + wn * 32 + nt * 16 + colL;
        bp[nt] = bias[c] + probs[c];
    }
#pragma unroll
    for (int mt = 0; mt < 4; ++mt)
#pragma unroll
        for (int nt = 0; nt < 2; ++nt) {
            int c = bC + wn * 32 + nt * 16 + colL;
#pragma unroll
            for (int reg = 0; reg < 4; ++reg) {
                int r = bR + wm * 64 + mt * 16 + quad * 4 + reg;
                C[(size_t)r * DOUT + c] = tanh_fast(acc[mt][nt][reg] + bp[nt]);
            }
        }
}

// ---------- fallback f32 GEMM (round-1, used if ws too small) ----------
__global__ __launch_bounds__(256) void gemm_tanh_kernel(
    const float* __restrict__ A, const float* __restrict__ Bw,
    const float* __restrict__ bias, const float* __restrict__ probs,
    float* __restrict__ C)
{
    __shared__ float As[16][128 + 4];
    __shared__ float Bs[16][128 + 4];
    const int tid = threadIdx.x;
    const int block_row = blockIdx.y * 128;
    const int block_col = blockIdx.x * 128;
    const int tr = (tid >> 4) << 3;
    const int tc = (tid & 15) << 3;
    const int a_row = tid >> 2;
    const int a_col = (tid & 3) << 2;
    const int b_row = tid >> 5;
    const int b_col = (tid & 31) << 2;
    const float* Aptr0 = A + (size_t)(block_row + a_row) * DIN + a_col;
    const float* Aptr1 = Aptr0 + (size_t)64 * DIN;
    const float* Bptr0 = Bw + (size_t)b_row * DOUT + block_col + b_col;
    const float* Bptr1 = Bptr0 + (size_t)8 * DOUT;
    float acc[8][8] = {};
    for (int k0 = 0; k0 < DIN; k0 += 16) {
        float4 a0 = *(const float4*)(Aptr0 + k0);
        float4 a1 = *(const float4*)(Aptr1 + k0);
        float4 b0 = *(const float4*)(Bptr0 + (size_t)k0 * DOUT);
        float4 b1 = *(const float4*)(Bptr1 + (size_t)k0 * DOUT);
        __syncthreads();
        As[a_col + 0][a_row] = a0.x;
        As[a_col + 1][a_row] = a0.y;
        As[a_col + 2][a_row] = a0.z;
        As[a_col + 3][a_row] = a0.w;
        As[a_col + 0][a_row + 64] = a1.x;
        As[a_col + 1][a_row + 64] = a1.y;
        As[a_col + 2][a_row + 64] = a1.z;
        As[a_col + 3][a_row + 64] = a1.w;
        *(float4*)&Bs[b_row][b_col]     = b0;
        *(float4*)&Bs[b_row + 8][b_col] = b1;
        __syncthreads();
#pragma unroll
        for (int kk = 0; kk < 16; ++kk) {
            float ar[8], br[8];
#pragma unroll
            for (int i = 0; i < 8; ++i) ar[i] = As[kk][tr + i];
#pragma unroll
            for (int i = 0; i < 8; ++i) br[i] = Bs[kk][tc + i];
#pragma unroll
            for (int i = 0; i < 8; ++i)
#pragma unroll
                for (int jj = 0; jj < 8; ++jj)
                    acc[i][jj] = fmaf(ar[i], br[jj], acc[i][jj]);
        }
    }
    float bp[8];
#pragma unroll
    for (int jj = 0; jj < 8; ++jj)
        bp[jj] = bias[block_col + tc + jj] + probs[block_col + tc + jj];
#pragma unroll
    for (int i = 0; i < 8; ++i) {
        float* crow = C + (size_t)(block_row + tr + i) * DOUT + block_col + tc;
#pragma unroll
        for (int jj = 0; jj < 8; ++jj)
            crow[jj] = tanh_fast(acc[i][jj] + bp[jj]);
    }
}

extern "C" void kernel_launch(void* const* d_in, const int* in_sizes, int n_in,
                              void* d_out, int out_size, void* d_ws, size_t ws_size,
                              hipStream_t stream) {
    const float* x  = (const float*)d_in[0];  // [4096, 2048]
    const float* W  = (const float*)d_in[1];  // [16, 2048, 2048]
    const float* cw = (const float*)d_in[2];  // [2048, 2048]
    const float* cb = (const float*)d_in[3];  // [2048]
    float* out = (float*)d_out;

    // ws layout: probs f32[2048] | x_hi | x_lo | wt_hi | wt_lo  (bf16 bits as u16)
    const size_t PROBS_B = 8192;
    const size_t XSZ = (size_t)BATCH * DIN;   // 8388608
    const size_t WSZ = (size_t)DIN * DOUT;    // 4194304
    const size_t need = PROBS_B + 2 * XSZ * 2 + 2 * WSZ * 2;  // 50,339,840 B

    float* probs = (float*)d_ws;
    probs_kernel<<<DOUT / 16, 256, 0, stream>>>(W, probs);

    if (ws_size >= need) {
        u16* xh = (u16*)((char*)d_ws + PROBS_B);
        u16* xl = xh + XSZ;
        u16* wh = xl + XSZ;
        u16* wl = wh + WSZ;

        convert_x_kernel<<<XSZ / 4 / 256, 256, 0, stream>>>(x, xh, xl);
        transpose_w_kernel<<<dim3(DOUT / 32, DIN / 32), 256, 0, stream>>>(cw, wh, wl);

        gemm_mfma_kernel<<<512, 512, 0, stream>>>(xh, xl, wh, wl, cb, probs, out);
    } else {
        dim3 grid(DOUT / 128, BATCH / 128);
        gemm_tanh_kernel<<<grid, 256, 0, stream>>>(x, cw, cb, probs, out);
    }
}

// Round 8
// 430.225 us; speedup vs baseline: 1.0221x; 1.0221x over previous
//
#include <hip/hip_runtime.h>
#include <math.h>

#define BATCH 4096
#define DIN   2048
#define DOUT  2048
#define DEPTH 16

typedef unsigned short u16;
typedef __attribute__((ext_vector_type(8))) short short8;  // 8 bf16 = 4 VGPRs
typedef __attribute__((ext_vector_type(4))) float f32x4;

// ---------- helpers ----------

__device__ static inline unsigned bf16_rn(float x) {
    unsigned u = __float_as_uint(x);
    return (u + 0x7FFFu + ((u >> 16) & 1u)) >> 16;  // RN-even to bf16 bits
}

__device__ static inline float tanh_fast(float z) {
    float zc = fminf(fmaxf(z, -15.0f), 15.0f);
    float e = __builtin_amdgcn_exp2f(zc * 2.8853900817779268f);  // exp(2z)
    return (e - 1.0f) * __builtin_amdgcn_rcpf(e + 1.0f);
}

__device__ static inline void async16(u16* lds, const u16* g) {
    __builtin_amdgcn_global_load_lds(
        (const __attribute__((address_space(1))) void*)g,
        (__attribute__((address_space(3))) void*)lds, 16, 0, 0);
}

// ---------- fused pre-pass: probs | convert_x | transpose_w ----------
// One launch instead of three. Grid layout (256 thr each):
//   [0, 128)          probs   (latency-bound, starts first)
//   [128, 8320)       convert_x (8192 blocks, BW-bound long pole)
//   [8320, 12416)     transpose_w (4096 blocks)
__global__ __launch_bounds__(256) void prepass_kernel(
    const float* __restrict__ x, const float* __restrict__ W,
    const float* __restrict__ cw,
    float* __restrict__ probs,
    u16* __restrict__ xh, u16* __restrict__ xl,
    u16* __restrict__ wh, u16* __restrict__ wl)
{
    const int b = blockIdx.x;
    const int tid = threadIdx.x;

    if (b < 128) {
        // ---- probs: probs[j] = (prod cos(W[d,j,g]))^2 / DIN ----
        int jl = tid >> 4, d = tid & 15;
        int j = b * 16 + jl;
        const float* p = W + (size_t)d * DIN * DOUT + (size_t)j * DOUT;
        float pr = cosf(p[0]) * cosf(p[1]) * cosf(p[2]);
#pragma unroll
        for (int off = 1; off < 16; off <<= 1) pr *= __shfl_xor(pr, off, 16);
        if (d == 0) probs[j] = pr * pr * (1.0f / (float)DIN);
    } else if (b < 8320) {
        // ---- convert_x: x -> hi/lo bf16 (RN split) ----
        int i = ((b - 128) * 256 + tid) * 4;
        float4 v = *(const float4*)(x + i);
        float vv[4] = {v.x, v.y, v.z, v.w};
        u16 hh[4], ll[4];
#pragma unroll
        for (int c = 0; c < 4; ++c) {
            unsigned hb = bf16_rn(vv[c]);
            hh[c] = (u16)hb;
            float r = vv[c] - __uint_as_float(hb << 16);
            ll[c] = (u16)bf16_rn(r);
        }
        ushort4 h, l;
        h.x = hh[0]; h.y = hh[1]; h.z = hh[2]; h.w = hh[3];
        l.x = ll[0]; l.y = ll[1]; l.z = ll[2]; l.w = ll[3];
        *(ushort4*)(xh + i) = h;
        *(ushort4*)(xl + i) = l;
    } else {
        // ---- transpose_w: W[k][n] -> Wt_hi/lo[n][k] ----
        __shared__ float t[32][33];
        int b2 = b - 8320;
        int n0 = (b2 & 63) * 32, k0 = (b2 >> 6) * 32;
        int tx = tid & 31, ty = tid >> 5;  // ty 0..7
#pragma unroll
        for (int i = 0; i < 4; ++i)
            t[ty + i * 8][tx] = cw[(size_t)(k0 + ty + i * 8) * DOUT + n0 + tx];
        __syncthreads();
#pragma unroll
        for (int i = 0; i < 4; ++i) {
            float v = t[tx][ty + i * 8];
            size_t o = (size_t)(n0 + ty + i * 8) * DIN + k0 + tx;
            unsigned hb = bf16_rn(v);
            wh[o] = (u16)hb;
            float r = v - __uint_as_float(hb << 16);
            wl[o] = (u16)bf16_rn(r);
        }
    }
}

// (standalone probs kept for the fallback path)
__global__ __launch_bounds__(256) void probs_kernel(const float* __restrict__ W,
                                                    float* __restrict__ probs) {
    int tid = threadIdx.x;
    int jl = tid >> 4, d = tid & 15;
    int j = blockIdx.x * 16 + jl;
    const float* p = W + (size_t)d * DIN * DOUT + (size_t)j * DOUT;
    float pr = cosf(p[0]) * cosf(p[1]) * cosf(p[2]);
#pragma unroll
    for (int off = 1; off < 16; off <<= 1) pr *= __shfl_xor(pr, off, 16);
    if (d == 0) probs[j] = pr * pr * (1.0f / (float)DIN);
}

// ---------- MFMA GEMM: C = tanh(x@W + bias + probs), bf16x3 ----------
// v4: 256x128 tile, 4 waves (2M x 2N), per-wave 128x64 output (8m x 4n
// 16x16 frags). Halves LDS-read bytes per MFMA vs v3 (24 ds_read_b128 ->
// 96 MFMA, 256 B/MFMA). Grid 256 = 1 block/CU exactly (16x16 tiles).
// Same verified v3 sync skeleton: 3 LDS buffers (144 KB), depth-2 prefetch,
// counted vmcnt(12), raw s_barrier + sched_barrier fences, setprio(1) MFMA.
// Staging: 48 chunks/tile (Ah 16 | Al 16 | Bh 8 | Bl 8, contiguous), wave w
// stages chunks [w*12, w*12+12); flattened chunk index c -> LDS el c*512.
// Rows of 32 bf16 (64B), XOR swizzle phys_quad = quad ^ ((row>>1)&3),
// pre-swizzled global source (rule #21). Frag/C-D math verified (m89/m91).
__global__ __launch_bounds__(256, 1) void gemm_mfma_kernel(
    const u16* __restrict__ xh, const u16* __restrict__ xl,
    const u16* __restrict__ wh, const u16* __restrict__ wl,
    const float* __restrict__ bias, const float* __restrict__ probs,
    float* __restrict__ C)
{
    // per buffer (u16 el): Ah[0,8192) Al[8192,16384) Bh[16384,20480) Bl[20480,24576)
    __shared__ __align__(16) u16 lds[3][24576];  // 144 KB -> 1 block/CU

    const int tid = threadIdx.x;
    const int lane = tid & 63;
    const int wave = tid >> 6;  // 0..3

    // T1: bijective XCD swizzle (256 blocks, 256 % 8 == 0). m-fastest within
    // an XCD chunk: each XCD holds ~2 B-panel pairs (2 MB) L2-hot.
    const int bid = blockIdx.x;
    const int swz = (bid & 7) * 32 + (bid >> 3);
    const int bR = (swz & 15) * 256;
    const int bC = (swz >> 4) * 128;

    // ---- staging: 12 chunks per wave, flattened chunk c = wave*12 + j ----
    const u16* psrc[12];
#pragma unroll
    for (int j = 0; j < 12; ++j) {
        int c = wave * 12 + j;
        const u16* base;
        int lrow;
        if (c < 16)      { base = xh + (size_t)bR * DIN; lrow = c * 16 + (lane >> 2); }
        else if (c < 32) { base = xl + (size_t)bR * DIN; lrow = (c - 16) * 16 + (lane >> 2); }
        else if (c < 40) { base = wh + (size_t)bC * DIN; lrow = (c - 32) * 16 + (lane >> 2); }
        else             { base = wl + (size_t)bC * DIN; lrow = (c - 40) * 16 + (lane >> 2); }
        int lq = (lane & 3) ^ ((lrow >> 1) & 3);  // pre-swizzled source
        psrc[j] = base + (size_t)lrow * DIN + lq * 8;
    }
    const int dst0 = wave * 12 * 512;  // el offset of this wave's first chunk

    // ---- per-wave output: rows wm*128 (8 m-tiles), cols wn*64 (4 n-tiles) ----
    const int wm = wave >> 1, wn = wave & 1;
    const int colL = lane & 15, quad = lane >> 4;

    int aoff[8], boff[4];
#pragma unroll
    for (int mt = 0; mt < 8; ++mt) {
        int r = wm * 128 + mt * 16 + colL;
        aoff[mt] = r * 32 + (quad ^ ((r >> 1) & 3)) * 8;           // Ah region
    }
#pragma unroll
    for (int nt = 0; nt < 4; ++nt) {
        int r = wn * 64 + nt * 16 + colL;
        boff[nt] = 16384 + r * 32 + (quad ^ ((r >> 1) & 3)) * 8;   // Bh region
    }

    f32x4 acc[8][4];
#pragma unroll
    for (int mt = 0; mt < 8; ++mt)
#pragma unroll
        for (int nt = 0; nt < 4; ++nt) acc[mt][nt] = (f32x4){0.f, 0.f, 0.f, 0.f};

    // prologue: issue tiles 0 -> buf0, 1 -> buf1 (24 loads in flight / wave)
#pragma unroll
    for (int j = 0; j < 12; ++j) async16(&lds[0][0] + dst0 + j * 512, psrc[j]);
#pragma unroll
    for (int j = 0; j < 12; ++j) async16(&lds[1][0] + dst0 + j * 512, psrc[j] + 32);

#pragma unroll 1
    for (int t = 0; t < 63; ++t) {
        const int cur = t % 3;

        asm volatile("s_waitcnt vmcnt(12)" ::: "memory");  // tile t done, t+1 flying
        __builtin_amdgcn_s_barrier();
        asm volatile("" ::: "memory");
        __builtin_amdgcn_sched_barrier(0);

        // issue tile t+2 into buf[(t+2)%3] (safe: all waves past barrier t
        // => iter t-1 reads consumed; see v3 ledger)
        if (t < 62) {
            u16* st = &lds[(t + 2) % 3][0] + dst0;
            const int kk = (t + 2) * 32;
#pragma unroll
            for (int j = 0; j < 12; ++j) async16(st + j * 512, psrc[j] + kk);
        }

        const u16* Lb = &lds[cur][0];
        short8 ah[8], al[8], bh[4], bl[4];
#pragma unroll
        for (int mt = 0; mt < 8; ++mt) {
            ah[mt] = *(const short8*)(Lb + aoff[mt]);
            al[mt] = *(const short8*)(Lb + 8192 + aoff[mt]);
        }
#pragma unroll
        for (int nt = 0; nt < 4; ++nt) {
            bh[nt] = *(const short8*)(Lb + boff[nt]);
            bl[nt] = *(const short8*)(Lb + 4096 + boff[nt]);
        }

        __builtin_amdgcn_s_setprio(1);
#pragma unroll
        for (int mt = 0; mt < 8; ++mt)
#pragma unroll
            for (int nt = 0; nt < 4; ++nt) {
                acc[mt][nt] = __builtin_amdgcn_mfma_f32_16x16x32_bf16(
                    ah[mt], bh[nt], acc[mt][nt], 0, 0, 0);
                acc[mt][nt] = __builtin_amdgcn_mfma_f32_16x16x32_bf16(
                    ah[mt], bl[nt], acc[mt][nt], 0, 0, 0);
                acc[mt][nt] = __builtin_amdgcn_mfma_f32_16x16x32_bf16(
                    al[mt], bh[nt], acc[mt][nt], 0, 0, 0);
            }
        __builtin_amdgcn_s_setprio(0);
    }

    // peeled final K-step (t = 63, buf 63%3 = 0): full drain, no prefetch
    {
        asm volatile("s_waitcnt vmcnt(0)" ::: "memory");
        __builtin_amdgcn_s_barrier();
        asm volatile("" ::: "memory");
        __builtin_amdgcn_sched_barrier(0);

        const u16* Lb = &lds[0][0];
        short8 ah[8], al[8], bh[4], bl[4];
#pragma unroll
        for (int mt = 0; mt < 8; ++mt) {
            ah[mt] = *(const short8*)(Lb + aoff[mt]);
            al[mt] = *(const short8*)(Lb + 8192 + aoff[mt]);
        }
#pragma unroll
        for (int nt = 0; nt < 4; ++nt) {
            bh[nt] = *(const short8*)(Lb + boff[nt]);
            bl[nt] = *(const short8*)(Lb + 4096 + boff[nt]);
        }
#pragma unroll
        for (int mt = 0; mt < 8; ++mt)
#pragma unroll
            for (int nt = 0; nt < 4; ++nt) {
                acc[mt][nt] = __builtin_amdgcn_mfma_f32_16x16x32_bf16(
                    ah[mt], bh[nt], acc[mt][nt], 0, 0, 0);
                acc[mt][nt] = __builtin_amdgcn_mfma_f32_16x16x32_bf16(
                    ah[mt], bl[nt], acc[mt][nt], 0, 0, 0);
                acc[mt][nt] = __builtin_amdgcn_mfma_f32_16x16x32_bf16(
                    al[mt], bh[nt], acc[mt][nt], 0, 0, 0);
            }
    }

    // epilogue: C/D map col=lane&15, row=quad*4+reg (verified m89/m91)
    float bp[4];
#pragma unroll
    for (int nt = 0; nt < 4; ++nt) {
        int c = bC + wn * 64 + nt * 16 + colL;
        bp[nt] = bias[c] + probs[c];
    }
#pragma unroll
    for (int mt = 0; mt < 8; ++mt)
#pragma unroll
        for (int nt = 0; nt < 4; ++nt) {
            int c = bC + wn * 64 + nt * 16 + colL;
#pragma unroll
            for (int reg = 0; reg < 4; ++reg) {
                int r = bR + wm * 128 + mt * 16 + quad * 4 + reg;
                C[(size_t)r * DOUT + c] = tanh_fast(acc[mt][nt][reg] + bp[nt]);
            }
        }
}

// ---------- fallback f32 GEMM (used if ws too small) ----------
__global__ __launch_bounds__(256) void gemm_tanh_kernel(
    const float* __restrict__ A, const float* __restrict__ Bw,
    const float* __restrict__ bias, const float* __restrict__ probs,
    float* __restrict__ C)
{
    __shared__ float As[16][128 + 4];
    __shared__ float Bs[16][128 + 4];
    const int tid = threadIdx.x;
    const int block_row = blockIdx.y * 128;
    const int block_col = blockIdx.x * 128;
    const int tr = (tid >> 4) << 3;
    const int tc = (tid & 15) << 3;
    const int a_row = tid >> 2;
    const int a_col = (tid & 3) << 2;
    const int b_row = tid >> 5;
    const int b_col = (tid & 31) << 2;
    const float* Aptr0 = A + (size_t)(block_row + a_row) * DIN + a_col;
    const float* Aptr1 = Aptr0 + (size_t)64 * DIN;
    const float* Bptr0 = Bw + (size_t)b_row * DOUT + block_col + b_col;
    const float* Bptr1 = Bptr0 + (size_t)8 * DOUT;
    float acc[8][8] = {};
    for (int k0 = 0; k0 < DIN; k0 += 16) {
        float4 a0 = *(const float4*)(Aptr0 + k0);
        float4 a1 = *(const float4*)(Aptr1 + k0);
        float4 b0 = *(const float4*)(Bptr0 + (size_t)k0 * DOUT);
        float4 b1 = *(const float4*)(Bptr1 + (size_t)k0 * DOUT);
        __syncthreads();
        As[a_col + 0][a_row] = a0.x;
        As[a_col + 1][a_row] = a0.y;
        As[a_col + 2][a_row] = a0.z;
        As[a_col + 3][a_row] = a0.w;
        As[a_col + 0][a_row + 64] = a1.x;
        As[a_col + 1][a_row + 64] = a1.y;
        As[a_col + 2][a_row + 64] = a1.z;
        As[a_col + 3][a_row + 64] = a1.w;
        *(float4*)&Bs[b_row][b_col]     = b0;
        *(float4*)&Bs[b_row + 8][b_col] = b1;
        __syncthreads();
#pragma unroll
        for (int kk = 0; kk < 16; ++kk) {
            float ar[8], br[8];
#pragma unroll
            for (int i = 0; i < 8; ++i) ar[i] = As[kk][tr + i];
#pragma unroll
            for (int i = 0; i < 8; ++i) br[i] = Bs[kk][tc + i];
#pragma unroll
            for (int i = 0; i < 8; ++i)
#pragma unroll
                for (int jj = 0; jj < 8; ++jj)
                    acc[i][jj] = fmaf(ar[i], br[jj], acc[i][jj]);
        }
    }
    float bp[8];
#pragma unroll
    for (int jj = 0; jj < 8; ++jj)
        bp[jj] = bias[block_col + tc + jj] + probs[block_col + tc + jj];
#pragma unroll
    for (int i = 0; i < 8; ++i) {
        float* crow = C + (size_t)(block_row + tr + i) * DOUT + block_col + tc;
#pragma unroll
        for (int jj = 0; jj < 8; ++jj)
            crow[jj] = tanh_fast(acc[i][jj] + bp[jj]);
    }
}

extern "C" void kernel_launch(void* const* d_in, const int* in_sizes, int n_in,
                              void* d_out, int out_size, void* d_ws, size_t ws_size,
                              hipStream_t stream) {
    const float* x  = (const float*)d_in[0];  // [4096, 2048]
    const float* W  = (const float*)d_in[1];  // [16, 2048, 2048]
    const float* cw = (const float*)d_in[2];  // [2048, 2048]
    const float* cb = (const float*)d_in[3];  // [2048]
    float* out = (float*)d_out;

    // ws layout: probs f32[2048] | x_hi | x_lo | wt_hi | wt_lo  (bf16 bits as u16)
    const size_t PROBS_B = 8192;
    const size_t XSZ = (size_t)BATCH * DIN;   // 8388608
    const size_t WSZ = (size_t)DIN * DOUT;    // 4194304
    const size_t need = PROBS_B + 2 * XSZ * 2 + 2 * WSZ * 2;  // 50,339,840 B

    float* probs = (float*)d_ws;

    if (ws_size >= need) {
        u16* xh = (u16*)((char*)d_ws + PROBS_B);
        u16* xl = xh + XSZ;
        u16* wh = xl + XSZ;
        u16* wl = wh + WSZ;

        // one fused pre-pass launch: probs + convert_x + transpose_w
        prepass_kernel<<<12416, 256, 0, stream>>>(x, W, cw, probs, xh, xl, wh, wl);

        gemm_mfma_kernel<<<256, 256, 0, stream>>>(xh, xl, wh, wl, cb, probs, out);
    } else {
        probs_kernel<<<DOUT / 16, 256, 0, stream>>>(W, probs);
        dim3 grid(DOUT / 128, BATCH / 128);
        gemm_tanh_kernel<<<grid, 256, 0, stream>>>(x, cw, cb, probs, out);
    }
}